// Round 5
// baseline (1125.305 us; speedup 1.0000x reference)
//
#include <hip/hip_runtime.h>

// Average-trace constant from the Python module (length 120).
__device__ __constant__ float AVG_D[120] = {
    0.0256f,0.0823f,0.1157f,0.1315f,0.1366f,0.1369f,0.1347f,0.1308f,0.1259f,0.1205f,
    0.1146f,0.1086f,0.1028f,0.0970f,0.0913f,0.0858f,0.0805f,0.0756f,0.0708f,0.0664f,
    0.0623f,0.0584f,0.0549f,0.0515f,0.0485f,0.0456f,0.0429f,0.0404f,0.0381f,0.0360f,
    0.0340f,0.0321f,0.0304f,0.0287f,0.0272f,0.0258f,0.0245f,0.0233f,0.0222f,0.0211f,
    0.0201f,0.0191f,0.0182f,0.0173f,0.0165f,0.0158f,0.0150f,0.0143f,0.0137f,0.0130f,
    0.0125f,0.0119f,0.0114f,0.0108f,0.0104f,0.0099f,0.0095f,0.0091f,0.0087f,0.0083f,
    0.0080f,0.0077f,0.0074f,0.0071f,0.0068f,0.0065f,0.0062f,0.0060f,0.0058f,0.0055f,
    0.0053f,0.0050f,0.0049f,0.0047f,0.0045f,0.0044f,0.0042f,0.0040f,0.0039f,0.0038f,
    0.0036f,0.0034f,0.0033f,0.0032f,0.0031f,0.0030f,0.0029f,0.0028f,0.0027f,0.0026f,
    0.0025f,0.0024f,0.0023f,0.0022f,0.0021f,0.0021f,0.0020f,0.0019f,0.0018f,0.0018f,
    0.0017f,0.0017f,0.0016f,0.0016f,0.0015f,0.0015f,0.0014f,0.0014f,0.0013f,0.0013f,
    0.0013f,0.0012f,0.0012f,0.0011f,0.0011f,0.0011f,0.0010f,0.0010f,0.0010f,0.0009f
};

__device__ __forceinline__ float sigf(float x) {
    return __builtin_amdgcn_rcpf(1.0f + __expf(-x));
}
__device__ __forceinline__ float tanh_fast(float x) {
    return fmaf(2.0f, __builtin_amdgcn_rcpf(1.0f + __expf(-2.0f * x)), -1.0f);
}

// d_ws float layout:
//   [0, 3840):    wt[j][q][32u] = W_hh1[(q*30+u)*30+j]   (u<30, pad to 32)
//   [3840, 3960): wcol[q*30+u]  = W_ih1[(q*30+u)*13+12]
__global__ void pack_weights(const float* __restrict__ w_ih1,
                             const float* __restrict__ w_hh1,
                             float* __restrict__ ws) {
    const int tid = threadIdx.x;
    for (int idx = tid; idx < 3840; idx += 256) {
        const int u = idx & 31, q = (idx >> 5) & 3, j = idx >> 7;
        ws[idx] = (u < 30) ? w_hh1[(q * 30 + u) * 30 + j] : 0.0f;
    }
    for (int idx = tid; idx < 120; idx += 256) ws[3840 + idx] = w_ih1[idx * 13 + 12];
}

// Block = 256 threads = 4 waves over the same 64 sequences (lane = seq).
// Wave q (readfirstlane -> uniform) computes gate q's 30 preactivation rows:
// 900 v_fma with s_load weights. Gate preacts exchanged via LDS; activations
// split by unit (8/8/8/6); h republished each step. 2 barriers/step.
// Grid 512 x 2-blocks/CU -> 2 waves/SIMD so stalls overlap across blocks.
__global__ __launch_bounds__(256, 2)
void lstm_trace_kernel(const float* __restrict__ feat,
                       const float* __restrict__ w_ih1,
                       const float* __restrict__ b1,
                       const float* __restrict__ w_ih2,
                       const float* __restrict__ w_hh2,
                       const float* __restrict__ b2,
                       const float* __restrict__ ws,
                       float* __restrict__ out) {
    __shared__ float gx[4][30][64];                   // gate preacts 30.7 KB
    __shared__ float hx[30][64];                      // new h        7.7 KB
    __shared__ float p2[4][4][64];                    // LSTM2 parts  4.1 KB
    __shared__ __align__(16) float out_s[64 * 124];   // h2 stage    31.7 KB
    // total 74.2 KB -> 2 blocks/CU (148.4 of 160 KB)

    const int tid  = threadIdx.x;
    const int lane = tid & 63;
    const int q    = __builtin_amdgcn_readfirstlane(tid >> 6);  // uniform gate id
    const int seq  = blockIdx.x * 64 + lane;
    const int base = (q < 3) ? 8 * q : 24;                      // activation units
    const int cnt  = (q == 3) ? 6 : 8;

    float f0[12];
    {
        const float4* fp = reinterpret_cast<const float4*>(feat + seq * 12);
        float4 A = fp[0], B = fp[1], C = fp[2];
        f0[0]=A.x; f0[1]=A.y; f0[2]=A.z; f0[3]=A.w;
        f0[4]=B.x; f0[5]=B.y; f0[6]=B.z; f0[7]=B.w;
        f0[8]=C.x; f0[9]=C.y; f0[10]=C.z; f0[11]=C.w;
    }

    // Per-sequence constant input projection for this wave's 30 gate rows
    // (rows q*30+u -> uniform addresses -> s_load weights).
    float projb[30];
#pragma unroll
    for (int u = 0; u < 30; u++) {
        const int r = q * 30 + u;
        float acc = b1[r];
#pragma unroll
        for (int d = 0; d < 12; d++) acc = fmaf(f0[d], w_ih1[r * 13 + d], acc);
        projb[u] = acc;
    }

    float h[30], c[8];
#pragma unroll
    for (int j = 0; j < 30; j++) h[j] = 0.0f;
#pragma unroll
    for (int k = 0; k < 8; k++) c[k] = 0.0f;
    float h2 = 0.0f, c2 = 0.0f;
    const float wh2[4] = { w_hh2[0], w_hh2[1], w_hh2[2], w_hh2[3] };
    const float bb2[4] = { b2[0], b2[1], b2[2], b2[3] };

#pragma unroll 1
    for (int t = 0; t < 120; t++) {
        const float at = AVG_D[t];

        // ---- phase 1: gate-q preactivations for all 30 units ----
        float acc[30];
#pragma unroll
        for (int u = 0; u < 30; u++)
            acc[u] = fmaf(at, ws[3840 + q * 30 + u], projb[u]);
#pragma unroll
        for (int j = 0; j < 30; j++) {
            const float hj = h[j];
            const float* wj = ws + j * 128 + q * 32;   // uniform -> s_load run of 30
#pragma unroll
            for (int u = 0; u < 30; u++) acc[u] = fmaf(hj, wj[u], acc[u]);
        }
#pragma unroll
        for (int u = 0; u < 30; u++) gx[q][u][lane] = acc[u];   // lane-contig

        __syncthreads();   // A: gx ready

        // ---- phase 2: activations for units [base, base+cnt) ----
        float p0 = 0.0f, p1 = 0.0f, p2v = 0.0f, p3 = 0.0f;
#pragma unroll
        for (int k = 0; k < 8; k++) {
            if (k < cnt) {
                const int U = base + k;
                const float gi = gx[0][U][lane];
                const float gf = gx[1][U][lane];
                const float gg = gx[2][U][lane];
                const float go = gx[3][U][lane];
                const float ck = sigf(gf) * c[k] + sigf(gi) * tanh_fast(gg);
                c[k] = ck;
                const float hk = sigf(go) * tanh_fast(ck);
                hx[U][lane] = hk;
                p0 = fmaf(hk, w_ih2[0 * 30 + U], p0);
                p1 = fmaf(hk, w_ih2[1 * 30 + U], p1);
                p2v = fmaf(hk, w_ih2[2 * 30 + U], p2v);
                p3 = fmaf(hk, w_ih2[3 * 30 + U], p3);
            }
        }
        p2[q][0][lane] = p0;
        p2[q][1][lane] = p1;
        p2[q][2][lane] = p2v;
        p2[q][3][lane] = p3;

        __syncthreads();   // B: hx, p2 ready

        // ---- phase 3: refresh h; wave 0 runs LSTM2 cell ----
#pragma unroll
        for (int j = 0; j < 30; j++) h[j] = hx[j][lane];

        if (q == 0) {
            float g0 = fmaf(h2, wh2[0], bb2[0]);
            float g1 = fmaf(h2, wh2[1], bb2[1]);
            float g2 = fmaf(h2, wh2[2], bb2[2]);
            float g3 = fmaf(h2, wh2[3], bb2[3]);
#pragma unroll
            for (int w = 0; w < 4; w++) {
                g0 += p2[w][0][lane];
                g1 += p2[w][1][lane];
                g2 += p2[w][2][lane];
                g3 += p2[w][3][lane];
            }
            c2 = sigf(g1) * c2 + sigf(g0) * tanh_fast(g2);
            h2 = sigf(g3) * tanh_fast(c2);
            out_s[lane * 124 + t] = h2;
        }
    }

    __syncthreads();
    // ---- coalesced flush: 64 seq x 120 t = 1920 float4, 256 threads ----
    float* outb = out + (size_t)blockIdx.x * 64 * 120;
#pragma unroll
    for (int it = 0; it < 8; it++) {
        const int fi = it * 256 + tid;
        if (fi < 1920) {
            const int s = fi / 30, j = fi % 30;
            const float4 v = *reinterpret_cast<const float4*>(&out_s[s * 124 + j * 4]);
            *reinterpret_cast<float4*>(&outb[s * 120 + j * 4]) = v;
        }
    }
}

extern "C" void kernel_launch(void* const* d_in, const int* in_sizes, int n_in,
                              void* d_out, int out_size, void* d_ws, size_t ws_size,
                              hipStream_t stream) {
    (void)in_sizes; (void)n_in; (void)out_size; (void)ws_size;
    const float* feat  = (const float*)d_in[0];
    const float* w_ih1 = (const float*)d_in[1];
    const float* w_hh1 = (const float*)d_in[2];
    const float* b1    = (const float*)d_in[3];
    const float* w_ih2 = (const float*)d_in[4];
    const float* w_hh2 = (const float*)d_in[5];
    const float* b2    = (const float*)d_in[6];
    float* ws  = (float*)d_ws;
    float* out = (float*)d_out;

    hipLaunchKernelGGL(pack_weights, dim3(1), dim3(256), 0, stream, w_ih1, w_hh1, ws);
    hipLaunchKernelGGL(lstm_trace_kernel, dim3(512), dim3(256), 0, stream,
                       feat, w_ih1, b1, w_ih2, w_hh2, b2, ws, out);
}

// Round 6
// 284.998 us; speedup vs baseline: 3.9485x; 3.9485x over previous
//
#include <hip/hip_runtime.h>

typedef __attribute__((ext_vector_type(8))) short bf16x8;
typedef __attribute__((ext_vector_type(4))) float f32x4;

// Average-trace constant from the Python module (length 120).
__device__ __constant__ float AVG_D[120] = {
    0.0256f,0.0823f,0.1157f,0.1315f,0.1366f,0.1369f,0.1347f,0.1308f,0.1259f,0.1205f,
    0.1146f,0.1086f,0.1028f,0.0970f,0.0913f,0.0858f,0.0805f,0.0756f,0.0708f,0.0664f,
    0.0623f,0.0584f,0.0549f,0.0515f,0.0485f,0.0456f,0.0429f,0.0404f,0.0381f,0.0360f,
    0.0340f,0.0321f,0.0304f,0.0287f,0.0272f,0.0258f,0.0245f,0.0233f,0.0222f,0.0211f,
    0.0201f,0.0191f,0.0182f,0.0173f,0.0165f,0.0158f,0.0150f,0.0143f,0.0137f,0.0130f,
    0.0125f,0.0119f,0.0114f,0.0108f,0.0104f,0.0099f,0.0095f,0.0091f,0.0087f,0.0083f,
    0.0080f,0.0077f,0.0074f,0.0071f,0.0068f,0.0065f,0.0062f,0.0060f,0.0058f,0.0055f,
    0.0053f,0.0050f,0.0049f,0.0047f,0.0045f,0.0044f,0.0042f,0.0040f,0.0039f,0.0038f,
    0.0036f,0.0034f,0.0033f,0.0032f,0.0031f,0.0030f,0.0029f,0.0028f,0.0027f,0.0026f,
    0.0025f,0.0024f,0.0023f,0.0022f,0.0021f,0.0021f,0.0020f,0.0019f,0.0018f,0.0018f,
    0.0017f,0.0017f,0.0016f,0.0016f,0.0015f,0.0015f,0.0014f,0.0014f,0.0013f,0.0013f,
    0.0013f,0.0012f,0.0012f,0.0011f,0.0011f,0.0011f,0.0010f,0.0010f,0.0010f,0.0009f
};

__device__ __forceinline__ float sigf(float x) {
    return __builtin_amdgcn_rcpf(1.0f + __expf(-x));
}
__device__ __forceinline__ float tanh_fast(float x) {
    return fmaf(2.0f, __builtin_amdgcn_rcpf(1.0f + __expf(-2.0f * x)), -1.0f);
}
__device__ __forceinline__ unsigned short tb(float x) {          // truncate fp32 -> bf16
    return (unsigned short)(__float_as_uint(x) >> 16);
}
__device__ __forceinline__ float fb(unsigned short h) {          // bf16 -> fp32
    return __uint_as_float(((unsigned)h) << 16);
}

// Weight matrix A[128 rows][32 k], row r = u*4+q (u=unit, q=gate i/f/g/o):
//   u<30,  k<30 : W_hh1[(q*30+u)*30+k]
//   u<30,  k==30: W_ih1[(q*30+u)*13+12]   (avg column; B[30]=AVG[t] absorbs it)
//   u==30, k<30 : W_ih2[q*30+k]           (LSTM2 input dot rides the same MFMA)
//   else 0
// ws layout (float*): ushort whi[4096] @0 (8KB, frag [T][lane][j]); ushort wlo @2048;
//                     float bconst[128] @4096; float wih1f[128*12] @4224
__global__ void pack_weights(const float* __restrict__ w_ih1,
                             const float* __restrict__ w_hh1,
                             const float* __restrict__ b1,
                             const float* __restrict__ w_ih2,
                             const float* __restrict__ b2,
                             float* __restrict__ ws) {
    unsigned short* whi = (unsigned short*)ws;
    unsigned short* wlo = (unsigned short*)(ws + 2048);
    float* bconst = ws + 4096;
    float* wih1f  = ws + 4224;
    const int tid = threadIdx.x;
    for (int idx = tid; idx < 4096; idx += 256) {
        const int T = idx >> 9, lane = (idx >> 3) & 63, j = idx & 7;
        const int r = 16 * T + (lane & 15);
        const int k = ((lane >> 4) & 3) * 8 + j;
        const int u = r >> 2, q = r & 3;
        float v = 0.0f;
        if (u < 30) {
            if (k < 30)       v = w_hh1[(q * 30 + u) * 30 + k];
            else if (k == 30) v = w_ih1[(q * 30 + u) * 13 + 12];
        } else if (u == 30 && k < 30) {
            v = w_ih2[q * 30 + k];
        }
        const unsigned short hi = tb(v);
        whi[idx] = hi;
        wlo[idx] = tb(v - fb(hi));
    }
    for (int r = tid; r < 128; r += 256) {
        const int u = r >> 2, q = r & 3;
        bconst[r] = (u < 30) ? b1[q * 30 + u] : ((u == 30) ? b2[q] : 0.0f);
    }
    for (int idx = tid; idx < 1536; idx += 256) {
        const int r = idx / 12, d = idx % 12;
        const int u = r >> 2, q = r & 3;
        wih1f[idx] = (u < 30) ? w_ih1[(q * 30 + u) * 13 + d] : 0.0f;
    }
}

// One wave = 16 sequences. Per step: D[8 tiles] = (Ahi+Alo)(Bhi+Blo)+projb via
// 3x8 chained MFMAs (lo*lo dropped); lane (s=lane&15, quad=lane>>4) gets i,f,g,o
// of unit 4T+quad in D[T][0..3]; unit 30 row = LSTM2 input dot (pipelined 1 step).
// h exchanged via per-wave LDS — intra-wave only, NO barriers in the hot loop.
// Block = 256 = 4 independent waves; grid 512 -> 2048 waves = 2/SIMD.
__global__ __launch_bounds__(256, 2)
void lstm_mfma_kernel(const float* __restrict__ feat,
                      const float* __restrict__ w_hh2,
                      const float* __restrict__ ws,
                      float* __restrict__ out) {
    __shared__ float hx_s[4][32 * 17];                // per-wave h buffer, 8.7 KB
    __shared__ __align__(16) float out_s[64 * 124];   // h2 staging, 31.7 KB

    const int tid  = threadIdx.x;
    const int lane = tid & 63;
    const int wv   = tid >> 6;          // wave in block
    const int s    = lane & 15;         // sequence slot within wave
    const int quad = lane >> 4;
    const int seq  = (blockIdx.x * 4 + wv) * 16 + s;
    float* hx = &hx_s[wv][0];

    // zero h(-1) incl. pad rows 30,31 (read by B-build, never rewritten)
    for (int i = lane; i < 544; i += 64) hx[i] = 0.0f;

    // ---- A fragments (weights), loaded once: [T][lane][8] bf16 hi/lo ----
    bf16x8 Ahi[8], Alo[8];
    {
        const unsigned short* whi = (const unsigned short*)ws;
        const unsigned short* wlo = (const unsigned short*)(ws + 2048);
#pragma unroll
        for (int T = 0; T < 8; T++) {
            Ahi[T] = *(const bf16x8*)(whi + T * 512 + lane * 8);
            Alo[T] = *(const bf16x8*)(wlo + T * 512 + lane * 8);
        }
    }

    // ---- per-sequence constant projection in C/D fragment layout ----
    float f0[12];
    {
        const float4* fp = reinterpret_cast<const float4*>(feat + seq * 12);
        float4 A = fp[0], B = fp[1], C = fp[2];
        f0[0]=A.x; f0[1]=A.y; f0[2]=A.z; f0[3]=A.w;
        f0[4]=B.x; f0[5]=B.y; f0[6]=B.z; f0[7]=B.w;
        f0[8]=C.x; f0[9]=C.y; f0[10]=C.z; f0[11]=C.w;
    }
    f32x4 projb[8];
    {
        const float* bconst = ws + 4096;
        const float* wih1f  = ws + 4224;
#pragma unroll
        for (int T = 0; T < 8; T++) {
#pragma unroll
            for (int g = 0; g < 4; g++) {
                const int r = 16 * T + 4 * quad + g;
                float acc = bconst[r];
#pragma unroll
                for (int d = 0; d < 12; d++) acc = fmaf(f0[d], wih1f[r * 12 + d], acc);
                projb[T][g] = acc;
            }
        }
    }

    float c1[8];
#pragma unroll
    for (int T = 0; T < 8; T++) c1[T] = 0.0f;
    float h2 = 0.0f, c2 = 0.0f;
    const float wh20 = w_hh2[0], wh21 = w_hh2[1], wh22 = w_hh2[2], wh23 = w_hh2[3];

#pragma unroll 1
    for (int t = 0; t <= 120; t++) {
        // ---- B fragment: h_{t-1} hi/lo + avg scalar in k=30 slot ----
        bf16x8 Bhi, Blo;
#pragma unroll
        for (int j = 0; j < 8; j++) {
            const int u = 8 * quad + j;                 // k index this lane holds
            const float hv = hx[u * 17 + s];
            const unsigned short hh = tb(hv);
            Bhi[j] = (short)hh;
            Blo[j] = (short)tb(hv - fb(hh));
        }
        if (quad == 3) {                                // k=30 -> AVG[t]
            const float at = (t < 120) ? AVG_D[t] : 0.0f;
            const unsigned short ah = tb(at);
            Bhi[6] = (short)ah;
            Blo[6] = (short)tb(at - fb(ah));
        }

        // ---- 24 MFMAs: D = Ahi*Bhi + Ahi*Blo + Alo*Bhi + projb ----
        f32x4 D[8];
#pragma unroll
        for (int T = 0; T < 8; T++)
            D[T] = __builtin_amdgcn_mfma_f32_16x16x32_bf16(Alo[T], Bhi, projb[T], 0, 0, 0);
#pragma unroll
        for (int T = 0; T < 8; T++)
            D[T] = __builtin_amdgcn_mfma_f32_16x16x32_bf16(Ahi[T], Blo, D[T], 0, 0, 0);
#pragma unroll
        for (int T = 0; T < 8; T++)
            D[T] = __builtin_amdgcn_mfma_f32_16x16x32_bf16(Ahi[T], Bhi, D[T], 0, 0, 0);

        // ---- LSTM2 cell for step t-1 (rows 120..123 = w_ih2 . h_{t-1} + b2) ----
        if (t >= 1 && quad == 2) {
            const float g0 = D[7][0] + h2 * wh20;
            const float g1 = D[7][1] + h2 * wh21;
            const float g2 = D[7][2] + h2 * wh22;
            const float g3 = D[7][3] + h2 * wh23;
            c2 = sigf(g1) * c2 + sigf(g0) * tanh_fast(g2);
            h2 = sigf(g3) * tanh_fast(c2);
            out_s[(wv * 16 + s) * 124 + (t - 1)] = h2;
        }

        // ---- LSTM1 activations: lane's unit u=4T+quad; write h_t to LDS ----
        if (t < 120) {
#pragma unroll
            for (int T = 0; T < 7; T++) {               // u = 4T+quad <= 27
                const float ci = sigf(D[T][0]);
                const float cf = sigf(D[T][1]);
                const float cg = tanh_fast(D[T][2]);
                const float co = sigf(D[T][3]);
                const float ck = cf * c1[T] + ci * cg;
                c1[T] = ck;
                hx[(4 * T + quad) * 17 + s] = co * tanh_fast(ck);
            }
            if (quad < 2) {                             // T=7: units 28,29 only
                const float ci = sigf(D[7][0]);
                const float cf = sigf(D[7][1]);
                const float cg = tanh_fast(D[7][2]);
                const float co = sigf(D[7][3]);
                const float ck = cf * c1[7] + ci * cg;
                c1[7] = ck;
                hx[(28 + quad) * 17 + s] = co * tanh_fast(ck);
            }
        }
    }

    __syncthreads();
    // ---- coalesced flush: 64 seq x 120 t = 1920 float4 ----
    float* outb = out + (size_t)blockIdx.x * 64 * 120;
#pragma unroll
    for (int it = 0; it < 8; it++) {
        const int fi = it * 256 + tid;
        if (fi < 1920) {
            const int sq = fi / 30, j = fi % 30;
            const float4 v = *reinterpret_cast<const float4*>(&out_s[sq * 124 + j * 4]);
            *reinterpret_cast<float4*>(&outb[sq * 120 + j * 4]) = v;
        }
    }
}

extern "C" void kernel_launch(void* const* d_in, const int* in_sizes, int n_in,
                              void* d_out, int out_size, void* d_ws, size_t ws_size,
                              hipStream_t stream) {
    (void)in_sizes; (void)n_in; (void)out_size; (void)ws_size;
    const float* feat  = (const float*)d_in[0];
    const float* w_ih1 = (const float*)d_in[1];
    const float* w_hh1 = (const float*)d_in[2];
    const float* b1    = (const float*)d_in[3];
    const float* w_ih2 = (const float*)d_in[4];
    const float* w_hh2 = (const float*)d_in[5];
    const float* b2    = (const float*)d_in[6];
    float* ws  = (float*)d_ws;
    float* out = (float*)d_out;

    hipLaunchKernelGGL(pack_weights, dim3(1), dim3(256), 0, stream,
                       w_ih1, w_hh1, b1, w_ih2, b2, ws);
    hipLaunchKernelGGL(lstm_mfma_kernel, dim3(512), dim3(256), 0, stream,
                       feat, w_hh2, ws, out);
}